// Round 1
// baseline (131.638 us; speedup 1.0000x reference)
//
#include <hip/hip_runtime.h>
#include <hip/hip_bf16.h>

#define B 32
#define O 64
#define M 128
#define H 4
#define E 64
#define CSTR 68   // context LDS stride: float4-aligned, (4m+e)%32 banks -> <=2-way (free)

__device__ __forceinline__ float tanh_fast(float x) {
    // tanh(x) = 1 - 2/(exp(2x)+1); safe at +-inf (rcp(inf)=0 -> +-1)
    float ex = __expf(x + x);
    float r  = __builtin_amdgcn_rcpf(ex + 1.0f);
    return fmaf(-2.0f, r, 1.0f);
}

__global__ __launch_bounds__(256) void attn_kernel(
    const float* __restrict__ query,   // [B,O,E]
    const float* __restrict__ context, // [B,M,E]
    const float* __restrict__ memory,  // [B,M,E]
    const float* __restrict__ W_ch,    // [E, H*E]
    const float* __restrict__ b_ch,    // [H*E]
    const float* __restrict__ w_logit, // [E]
    const float* __restrict__ b_logit, // [1]
    const float* __restrict__ W_rh,    // [H*E, E]
    const float* __restrict__ b_rh,    // [E]
    const float* __restrict__ temp,    // [1]
    float* __restrict__ out)           // [B,O,E]
{
    const int t  = threadIdx.x;
    const int bo = blockIdx.x;     // b*O + o
    const int b  = bo >> 6;        // O = 64

    __shared__ float s_ctx[M * CSTR];      // 34816 B
    __shared__ float s_q[H * CSTR];        // q heads, padded
    __shared__ float s_qrow[E];
    __shared__ float s_wl[E];
    __shared__ float s_logit[M * H];       // p = m*4+h
    __shared__ float s_prob[M * H];
    __shared__ float s_red[256];
    __shared__ float s_heads[H * E];
    __shared__ float s_sum[H];

    // ---- stage context rows for this batch into LDS (float4, coalesced) ----
    const float* ctx = context + b * (M * E);
    #pragma unroll
    for (int i = 0; i < 8; ++i) {
        int idx = i * 1024 + t * 4;            // flat [m*64+e]
        float4 v = *(const float4*)(ctx + idx);
        int m = idx >> 6, e = idx & 63;
        *(float4*)(&s_ctx[m * CSTR + e]) = v;
    }
    if (t < 64)                  s_qrow[t]      = query[bo * 64 + t];
    else if (t < 128)            s_wl[t - 64]   = w_logit[t - 64];
    __syncthreads();

    // ---- q projection: 256 columns, one per thread (64 MACs each) ----
    {
        int c = t;
        float acc = b_ch[c];
        #pragma unroll 8
        for (int k = 0; k < 64; ++k)
            acc = fmaf(s_qrow[k], W_ch[k * 256 + c], acc);
        s_q[(c >> 6) * CSTR + (c & 63)] = acc;
    }
    __syncthreads();

    // ---- tanh + logit dot: thread handles pairs p = t, t+256 ; p=(m*4+h) ----
    const float bl   = b_logit[0];
    const float invt = 1.0f / temp[0];
    #pragma unroll
    for (int pi = 0; pi < 2; ++pi) {
        int p = t + pi * 256;
        int m = p >> 2, h = p & 3;
        const float* crow = &s_ctx[m * CSTR];
        const float* qrow = &s_q[h * CSTR];
        float acc = 0.f;
        #pragma unroll
        for (int e = 0; e < 64; e += 4) {
            float4 cv = *(const float4*)(crow + e);
            float4 qv = *(const float4*)(qrow + e);
            float4 wv = *(const float4*)(&s_wl[e]);
            acc = fmaf(tanh_fast(cv.x + qv.x), wv.x, acc);
            acc = fmaf(tanh_fast(cv.y + qv.y), wv.y, acc);
            acc = fmaf(tanh_fast(cv.z + qv.z), wv.z, acc);
            acc = fmaf(tanh_fast(cv.w + qv.w), wv.w, acc);
        }
        s_logit[p] = (acc + bl) * invt;
    }
    __syncthreads();

    // ---- softmax over m per h (tree preserves h-class: s multiples of 4) ----
    float l0 = s_logit[t];
    float l1 = s_logit[t + 256];
    s_red[t] = fmaxf(l0, l1);
    __syncthreads();
    #pragma unroll
    for (int s = 128; s >= 4; s >>= 1) {
        if (t < s) s_red[t] = fmaxf(s_red[t], s_red[t + s]);
        __syncthreads();
    }
    float mx = s_red[t & 3];
    __syncthreads();
    float e0 = __expf(l0 - mx);
    float e1 = __expf(l1 - mx);
    s_prob[t]       = e0;
    s_prob[t + 256] = e1;
    s_red[t] = e0 + e1;
    __syncthreads();
    #pragma unroll
    for (int s = 128; s >= 4; s >>= 1) {
        if (t < s) s_red[t] += s_red[t + s];
        __syncthreads();
    }
    if (t < 4) s_sum[t] = s_red[t];
    __syncthreads();

    // ---- heads: weighted sum of memory over m, + leaky relu ----
    {
        int hh = t >> 6, e = t & 63;
        float rd = 1.0f / s_sum[hh];
        const float* mem = memory + b * (M * E);
        float acc = 0.f;
        #pragma unroll 4
        for (int m = 0; m < M; ++m)
            acc = fmaf(s_prob[m * 4 + hh], mem[m * 64 + e], acc);
        acc *= rd;
        s_heads[t] = (acc > 0.f) ? acc : 0.01f * acc;
    }
    __syncthreads();

    // ---- output projection: 4 waves x 64 rows each, then LDS reduce ----
    {
        int w = t >> 6, e2 = t & 63;
        const float* wr = W_rh + w * 64 * 64;
        const float* hd = &s_heads[w * 64];
        float p = 0.f;
        #pragma unroll 8
        for (int j = 0; j < 64; ++j)
            p = fmaf(hd[j], wr[j * 64 + e2], p);
        s_red[t] = p;
    }
    __syncthreads();
    if (t < 64) {
        float o = s_red[t] + s_red[t + 64] + s_red[t + 128] + s_red[t + 192] + b_rh[t];
        out[bo * 64 + t] = o;
    }
}

extern "C" void kernel_launch(void* const* d_in, const int* in_sizes, int n_in,
                              void* d_out, int out_size, void* d_ws, size_t ws_size,
                              hipStream_t stream) {
    const float* query   = (const float*)d_in[0];
    const float* context = (const float*)d_in[1];
    const float* memory  = (const float*)d_in[2];
    const float* W_ch    = (const float*)d_in[3];
    const float* b_ch    = (const float*)d_in[4];
    const float* w_logit = (const float*)d_in[5];
    const float* b_logit = (const float*)d_in[6];
    const float* W_rh    = (const float*)d_in[7];
    const float* b_rh    = (const float*)d_in[8];
    const float* temp    = (const float*)d_in[9];
    float* out = (float*)d_out;

    attn_kernel<<<B * O, 256, 0, stream>>>(query, context, memory, W_ch, b_ch,
                                           w_logit, b_logit, W_rh, b_rh, temp, out);
}

// Round 2
// 110.670 us; speedup vs baseline: 1.1895x; 1.1895x over previous
//
#include <hip/hip_runtime.h>
#include <hip/hip_fp16.h>

#define B 32
#define O 64
#define M 128
#define H 4
#define E 64
#define CS 132   // half-stride of transposed ctx rows: bank = (2e+lane)%32 -> 2-way (free)

// broadcast lane's value to all lanes via SALU (v_readlane), off the LDS pipe
__device__ __forceinline__ float rl(float v, int lane) {
    return __uint_as_float(__builtin_amdgcn_readlane(__float_as_uint(v), lane));
}

__device__ __forceinline__ float tanh_fast(float x) {
    // tanh(x) = 1 - 2/(exp(2x)+1); safe at +-inf (rcp(inf)=0 -> +-1)
    float ex = __expf(x + x);
    float r  = __builtin_amdgcn_rcpf(ex + 1.0f);
    return fmaf(-2.0f, r, 1.0f);
}

__global__ __launch_bounds__(256) void attn_kernel(
    const float* __restrict__ query,   // [B,O,E]
    const float* __restrict__ context, // [B,M,E]
    const float* __restrict__ memory,  // [B,M,E]
    const float* __restrict__ W_ch,    // [E, H*E]
    const float* __restrict__ b_ch,    // [H*E]
    const float* __restrict__ w_logit, // [E]
    const float* __restrict__ b_logit, // [1]
    const float* __restrict__ W_rh,    // [H*E, E]
    const float* __restrict__ b_rh,    // [E]
    const float* __restrict__ temp,    // [1]
    float* __restrict__ out)           // [B,O,E]
{
    const int t    = threadIdx.x;
    const int lane = t & 63;
    const int w    = t >> 6;       // wave id == head h
    const int bo   = blockIdx.x;
    const int b    = bo >> 6;      // O = 64

    __shared__ __half s_ctxT[E * CS];  // transposed ctx, fp16: [e][m], 16896 B
    __shared__ float  s_red[256];

    // ---- stage context transposed fp16: lane's half2 (e,2m..2m+1) ----
    const float* ctx = context + b * (M * E);
    {
        int e0 = (t & 15) * 4;     // 16 threads cover e = 0..63 (float4 each)
        int mp = (t >> 4);         // 16 groups x 4 passes cover 64 m-pairs
        __half2* dst = (__half2*)s_ctxT;
        #pragma unroll
        for (int pq = 0; pq < 4; ++pq) {
            int col = mp + 16 * pq;        // m-pair index, m0 = 2*col
            int m0  = 2 * col;
            float4 r0 = *(const float4*)(ctx + m0 * E + e0);
            float4 r1 = *(const float4*)(ctx + (m0 + 1) * E + e0);
            __half2 h0, h1, h2, h3;
            h0.x = __float2half(r0.x); h0.y = __float2half(r1.x);
            h1.x = __float2half(r0.y); h1.y = __float2half(r1.y);
            h2.x = __float2half(r0.z); h2.y = __float2half(r1.z);
            h3.x = __float2half(r0.w); h3.y = __float2half(r1.w);
            dst[(e0 + 0) * (CS / 2) + col] = h0;
            dst[(e0 + 1) * (CS / 2) + col] = h1;
            dst[(e0 + 2) * (CS / 2) + col] = h2;
            dst[(e0 + 3) * (CS / 2) + col] = h3;
        }
    }

    // ---- q projection (overlaps staging): lane e of wave w -> q[w][e] ----
    float qv;
    {
        float qq  = query[bo * E + lane];      // lane k holds query[bo][k]
        float acc = b_ch[t];                   // column c = t = w*64+lane
        const float* Wc = W_ch + w * 64 + lane;
        #pragma unroll 16
        for (int k = 0; k < 64; ++k)
            acc = fmaf(rl(qq, k), Wc[k * 256], acc);
        qv = acc;
    }
    float wlv = w_logit[lane];

    __syncthreads();   // ctx_T ready

    // ---- tanh + logit dot: wave w = head, lane covers m = 2*lane, 2*lane+1 ----
    float acc0 = 0.f, acc1 = 0.f;
    const __half2* ctxT2 = (const __half2*)s_ctxT;
    #pragma unroll 8
    for (int e = 0; e < 64; ++e) {
        __half2 c2 = ctxT2[e * (CS / 2) + lane];
        float2 cf  = __half22float2(c2);
        float qe   = rl(qv, e);
        float we   = rl(wlv, e);
        acc0 = fmaf(tanh_fast(cf.x + qe), we, acc0);
        acc1 = fmaf(tanh_fast(cf.y + qe), we, acc1);
    }

    // ---- softmax over m (wave-local butterfly, no barriers) ----
    const float bl   = b_logit[0];
    const float invt = 1.0f / temp[0];
    float l0 = (acc0 + bl) * invt;
    float l1 = (acc1 + bl) * invt;
    float mx = fmaxf(l0, l1);
    #pragma unroll
    for (int s = 1; s < 64; s <<= 1)
        mx = fmaxf(mx, __shfl_xor(mx, s));
    float e0v = __expf(l0 - mx);
    float e1v = __expf(l1 - mx);
    float sum = e0v + e1v;
    #pragma unroll
    for (int s = 1; s < 64; s <<= 1)
        sum += __shfl_xor(sum, s);
    float rs = __builtin_amdgcn_rcpf(sum);

    // ---- heads: weighted sum of memory; probs broadcast via readlane ----
    float hacc = 0.f;
    {
        const float* mem = memory + b * (M * E) + lane;   // lane = e
        #pragma unroll 8
        for (int mh = 0; mh < 64; ++mh) {
            float pe = rl(e0v, mh);                        // prob[m=2*mh]
            float po = rl(e1v, mh);                        // prob[m=2*mh+1]
            hacc = fmaf(pe, mem[(2 * mh) * E], hacc);
            hacc = fmaf(po, mem[(2 * mh + 1) * E], hacc);
        }
    }
    hacc *= rs;
    float hv = (hacc > 0.f) ? hacc : 0.01f * hacc;  // leaky relu; heads[w][lane]

    // ---- out projection: wave w covers W_rh rows w*64..w*64+63 ----
    {
        float pacc = 0.f;
        const float* Wr = W_rh + (w * 64) * 64 + lane;    // lane = e'
        #pragma unroll 16
        for (int j = 0; j < 64; ++j)
            pacc = fmaf(rl(hv, j), Wr[j * 64], pacc);
        s_red[t] = pacc;
    }
    __syncthreads();
    if (t < 64) {
        float o = s_red[t] + s_red[t + 64] + s_red[t + 128] + s_red[t + 192] + b_rh[t];
        out[bo * 64 + t] = o;
    }
}

extern "C" void kernel_launch(void* const* d_in, const int* in_sizes, int n_in,
                              void* d_out, int out_size, void* d_ws, size_t ws_size,
                              hipStream_t stream) {
    const float* query   = (const float*)d_in[0];
    const float* context = (const float*)d_in[1];
    const float* memory  = (const float*)d_in[2];
    const float* W_ch    = (const float*)d_in[3];
    const float* b_ch    = (const float*)d_in[4];
    const float* w_logit = (const float*)d_in[5];
    const float* b_logit = (const float*)d_in[6];
    const float* W_rh    = (const float*)d_in[7];
    const float* b_rh    = (const float*)d_in[8];
    const float* temp    = (const float*)d_in[9];
    float* out = (float*)d_out;

    attn_kernel<<<B * O, 256, 0, stream>>>(query, context, memory, W_ch, b_ch,
                                           w_logit, b_logit, W_rh, b_rh, temp, out);
}

// Round 3
// 109.982 us; speedup vs baseline: 1.1969x; 1.0063x over previous
//
#include <hip/hip_runtime.h>
#include <hip/hip_fp16.h>

#define B 32
#define O 64
#define M 128
#define H 4
#define E 64
#define CW 66                 // ctx row stride in WORDS (half2 units): bank=(2e+lane)%32 -> 2-way (free)
#define SC  2.88539008177792681f   // 2*log2(e): tanh(x)=1-2/(1+exp2(SC*x))
#define LOG2E 1.44269504088896341f

#if __has_builtin(__builtin_amdgcn_exp2f)
#define EXP2F(x) __builtin_amdgcn_exp2f(x)
#else
#define EXP2F(x) __exp2f(x)
#endif

// broadcast lane's value to all lanes (v_readlane, SALU-ish: no LDS traffic)
__device__ __forceinline__ float rl(float v, int lane) {
    return __uint_as_float(__builtin_amdgcn_readlane(__float_as_uint(v), lane));
}

__global__ __launch_bounds__(256) void attn_kernel(
    const float* __restrict__ query,   // [B,O,E]
    const float* __restrict__ context, // [B,M,E]
    const float* __restrict__ memory,  // [B,M,E]
    const float* __restrict__ W_ch,    // [E, H*E]
    const float* __restrict__ b_ch,    // [H*E]
    const float* __restrict__ w_logit, // [E]
    const float* __restrict__ b_logit, // [1]
    const float* __restrict__ W_rh,    // [H*E, E]
    const float* __restrict__ b_rh,    // [E]
    const float* __restrict__ temp,    // [1]
    float* __restrict__ out)           // [B,O,E]
{
    const int t    = threadIdx.x;
    const int lane = t & 63;
    const int w    = t >> 6;       // wave id == head h
    const int bo   = blockIdx.x;
    const int b    = bo >> 6;      // O = 64

    __shared__ __half2 s_ctxT[E * CW]; // transposed, PRESCALED (x SC) fp16: [e][m-pair], 16896 B
    __shared__ float   s_red[256];

    // ---- stage context transposed fp16, prescaled by SC ----
    // thread t: e-quad e0 = 4*(t>>4), m-pair col = (t&15) + 16*pq
    // write bank = (8*(t>>4) + (t&15) + 16pq) % 32 -> exact 2-way (free)
    const float* ctx = context + b * (M * E);
    {
        int e0 = 4 * (t >> 4);
        int cb = t & 15;
        #pragma unroll
        for (int pq = 0; pq < 4; ++pq) {
            int col = cb + 16 * pq;        // m-pair index, m0 = 2*col
            int m0  = 2 * col;
            float4 r0 = *(const float4*)(ctx + m0 * E + e0);
            float4 r1 = *(const float4*)(ctx + (m0 + 1) * E + e0);
            __half2 h0, h1, h2, h3;
            h0.x = __float2half_rn(r0.x * SC); h0.y = __float2half_rn(r1.x * SC);
            h1.x = __float2half_rn(r0.y * SC); h1.y = __float2half_rn(r1.y * SC);
            h2.x = __float2half_rn(r0.z * SC); h2.y = __float2half_rn(r1.z * SC);
            h3.x = __float2half_rn(r0.w * SC); h3.y = __float2half_rn(r1.w * SC);
            s_ctxT[(e0 + 0) * CW + col] = h0;
            s_ctxT[(e0 + 1) * CW + col] = h1;
            s_ctxT[(e0 + 2) * CW + col] = h2;
            s_ctxT[(e0 + 3) * CW + col] = h3;
        }
    }

    // ---- q projection (overlaps staging): lane e of wave w -> q[w][e], prescaled ----
    float qv;
    {
        float qq  = query[bo * E + lane];      // lane k holds query[bo][k]
        float acc = b_ch[t];                   // column c = t = w*64+lane
        const float* Wc = W_ch + w * 64 + lane;
        #pragma unroll 16
        for (int k = 0; k < 64; ++k)
            acc = fmaf(rl(qq, k), Wc[k * 256], acc);
        qv = acc * SC;                         // prescale: x' = SC*(c+q)
    }
    float wlv = w_logit[lane];

    __syncthreads();   // ctx ready

    // ---- tanh + logit dot: wave w = head, lane covers m = 2*lane, 2*lane+1 ----
    // tanh(x) = 1 - 2*rcp(1 + exp2(x'))  with x' prescaled; raw v_exp_f32/v_rcp_f32
    float acc0 = 0.f, acc1 = 0.f;
    #pragma unroll 8
    for (int e = 0; e < 64; ++e) {
        __half2 c2 = s_ctxT[e * CW + lane];
        float2 cf  = __half22float2(c2);
        float qe   = rl(qv, e);
        float we   = rl(wlv, e);
        float ex0  = EXP2F(cf.x + qe);
        float ex1  = EXP2F(cf.y + qe);
        float r0   = __builtin_amdgcn_rcpf(ex0 + 1.0f);
        float r1   = __builtin_amdgcn_rcpf(ex1 + 1.0f);
        acc0 = fmaf(fmaf(-2.0f, r0, 1.0f), we, acc0);
        acc1 = fmaf(fmaf(-2.0f, r1, 1.0f), we, acc1);
    }

    // ---- softmax over m (wave butterfly); logits pre-multiplied by log2e so exp = v_exp ----
    const float bl  = b_logit[0];
    const float lsc = (1.0f / temp[0]) * LOG2E;
    float l0 = (acc0 + bl) * lsc;
    float l1 = (acc1 + bl) * lsc;
    float mx = fmaxf(l0, l1);
    #pragma unroll
    for (int s = 1; s < 64; s <<= 1)
        mx = fmaxf(mx, __shfl_xor(mx, s));
    float e0v = EXP2F(l0 - mx);      // exp2(log2e*(z-m)) == exp(z-m): softmax exact
    float e1v = EXP2F(l1 - mx);
    float sum = e0v + e1v;
    #pragma unroll
    for (int s = 1; s < 64; s <<= 1)
        sum += __shfl_xor(sum, s);
    float rs = __builtin_amdgcn_rcpf(sum);

    // ---- heads: weighted sum of memory; probs broadcast via readlane ----
    float hacc = 0.f;
    {
        const float* mem = memory + b * (M * E) + lane;   // lane = e
        #pragma unroll 8
        for (int mh = 0; mh < 64; ++mh) {
            float pe = rl(e0v, mh);                        // prob[m=2*mh]
            float po = rl(e1v, mh);                        // prob[m=2*mh+1]
            hacc = fmaf(pe, mem[(2 * mh) * E], hacc);
            hacc = fmaf(po, mem[(2 * mh + 1) * E], hacc);
        }
    }
    hacc *= rs;
    float hv = (hacc > 0.f) ? hacc : 0.01f * hacc;  // leaky relu; heads[w][lane]

    // ---- out projection: wave w covers W_rh rows w*64..w*64+63 ----
    {
        float pacc = 0.f;
        const float* Wr = W_rh + (w * 64) * 64 + lane;    // lane = e'
        #pragma unroll 16
        for (int j = 0; j < 64; ++j)
            pacc = fmaf(rl(hv, j), Wr[j * 64], pacc);
        s_red[t] = pacc;
    }
    __syncthreads();
    if (t < 64) {
        float o = s_red[t] + s_red[t + 64] + s_red[t + 128] + s_red[t + 192] + b_rh[t];
        out[bo * 64 + t] = o;
    }
}

extern "C" void kernel_launch(void* const* d_in, const int* in_sizes, int n_in,
                              void* d_out, int out_size, void* d_ws, size_t ws_size,
                              hipStream_t stream) {
    const float* query   = (const float*)d_in[0];
    const float* context = (const float*)d_in[1];
    const float* memory  = (const float*)d_in[2];
    const float* W_ch    = (const float*)d_in[3];
    const float* b_ch    = (const float*)d_in[4];
    const float* w_logit = (const float*)d_in[5];
    const float* b_logit = (const float*)d_in[6];
    const float* W_rh    = (const float*)d_in[7];
    const float* b_rh    = (const float*)d_in[8];
    const float* temp    = (const float*)d_in[9];
    float* out = (float*)d_out;

    attn_kernel<<<B * O, 256, 0, stream>>>(query, context, memory, W_ch, b_ch,
                                           w_logit, b_logit, W_rh, b_rh, temp, out);
}

// Round 4
// 106.698 us; speedup vs baseline: 1.2337x; 1.0308x over previous
//
#include <hip/hip_runtime.h>
#include <hip/hip_fp16.h>

#define B 32
#define O 64
#define M 128
#define H 4
#define E 64
#define SC 2.88539008177792681f     // 2*log2(e): tanh(x) = 1 - 2*rcp(1+exp2(SC*x))
#define LOG2E 1.44269504088896341f

#if __has_builtin(__builtin_amdgcn_exp2f)
#define EXP2F(x) __builtin_amdgcn_exp2f(x)
#else
#define EXP2F(x) __exp2f(x)
#endif

__device__ __forceinline__ float rl(float v, int lane) {
    return __uint_as_float(__builtin_amdgcn_readlane(__float_as_uint(v), lane));
}
__device__ __forceinline__ unsigned pk2h(float a, float b) {
    return (unsigned)__half_as_ushort(__float2half_rn(a)) |
           ((unsigned)__half_as_ushort(__float2half_rn(b)) << 16);
}

// ============ prep: blocks 0..31 convert ctx(->T,x SC,fp16) + mem(fp16);
//              blocks 32..543: q_all = (query@W_ch + b_ch)*SC, 4 rows/block ====
__global__ __launch_bounds__(256) void prep_kernel(
    const float* __restrict__ query, const float* __restrict__ context,
    const float* __restrict__ memory, const float* __restrict__ W_ch,
    const float* __restrict__ b_ch,
    __half* __restrict__ ctx_T, __half* __restrict__ mem_h, float* __restrict__ q_all)
{
    __shared__ float s[128 * 68];          // conv path: ctx staged stride-68
    const int t = threadIdx.x, blk = blockIdx.x;

    if (blk < 32) {
        const int b = blk;
        const float* ctx = context + b * (M * E);
        #pragma unroll
        for (int i = 0; i < 8; ++i) {       // stage ctx coalesced
            int idx = i * 1024 + t * 4;
            float4 v = *(const float4*)(ctx + idx);
            int m = idx >> 6, e = idx & 63;
            *(float4*)(&s[m * 68 + e]) = v;
        }
        // memory -> fp16 (no transpose), coalesced 8B stores
        {
            const float* mem = memory + b * (M * E);
            __half* mh = mem_h + (size_t)b * (M * E);
            #pragma unroll
            for (int i = 0; i < 8; ++i) {
                int idx = i * 1024 + t * 4;
                float4 v = *(const float4*)(mem + idx);
                *(uint2*)(mh + idx) = make_uint2(pk2h(v.x, v.y), pk2h(v.z, v.w));
            }
        }
        __syncthreads();
        // transpose out: thread -> (e = t>>2, m-block = (t&3)*32), 64B store
        {
            int e = t >> 2, mb = (t & 3) * 32;
            uint4 o[4];
            #pragma unroll
            for (int qd = 0; qd < 4; ++qd) {
                unsigned u[4];
                #pragma unroll
                for (int k = 0; k < 4; ++k) {
                    int m0 = mb + qd * 8 + 2 * k;
                    u[k] = pk2h(s[m0 * 68 + e] * SC, s[(m0 + 1) * 68 + e] * SC);
                }
                o[qd] = make_uint4(u[0], u[1], u[2], u[3]);
            }
            uint4* dst = (uint4*)(ctx_T + (size_t)b * (E * M) + e * M + mb);
            dst[0] = o[0]; dst[1] = o[1]; dst[2] = o[2]; dst[3] = o[3];
        }
    } else {
        const int r0 = (blk - 32) * 4;      // 4 query rows (bo indices)
        // stage 4x64 query transposed into s[k*4+r]
        s[t] = query[(r0 + (t & 3)) * 64 + (t >> 2)];
        __syncthreads();
        float bc = b_ch[t];
        float a0 = bc, a1 = bc, a2 = bc, a3 = bc;
        #pragma unroll 8
        for (int k = 0; k < 64; ++k) {
            float4 qv = *(const float4*)(&s[k * 4]);   // uniform ds_read_b128
            float wv = W_ch[k * 256 + t];
            a0 = fmaf(qv.x, wv, a0);
            a1 = fmaf(qv.y, wv, a1);
            a2 = fmaf(qv.z, wv, a2);
            a3 = fmaf(qv.w, wv, a3);
        }
        float* qa = q_all + (size_t)r0 * 256 + t;
        qa[0] = a0 * SC; qa[256] = a1 * SC; qa[512] = a2 * SC; qa[768] = a3 * SC;
    }
}

// ============ main: per (b,o) block. tanh+softmax per-wave-head, cooperative heads ====
__global__ __launch_bounds__(256) void attn_main(
    const __half* __restrict__ ctx_T, const __half* __restrict__ mem_h,
    const float* __restrict__ q_all, const float* __restrict__ w_logit,
    const float* __restrict__ b_logit, const float* __restrict__ temp,
    __half* __restrict__ heads_h)
{
    __shared__ __half s_ctx[E * M];     // [e][m] 16KB, linear
    __shared__ __half s_mem[M * E];     // [m][e] 16KB, linear
    __shared__ float  s_prob[M * H];    // [m][h]  2KB
    __shared__ float  s_part[H * 4 * E]; // [h][wave][e] 4KB

    const int t = threadIdx.x, lane = t & 63, w = t >> 6;
    const int bo = blockIdx.x, b = bo >> 6;

    // stage ctx_T[b], mem_h[b] (16KB each, dwordx4)
    {
        const uint4* g1 = (const uint4*)(ctx_T + (size_t)b * (E * M));
        const uint4* g2 = (const uint4*)(mem_h + (size_t)b * (M * E));
        uint4* l1 = (uint4*)s_ctx;
        uint4* l2 = (uint4*)s_mem;
        #pragma unroll
        for (int p = 0; p < 4; ++p) {
            l1[p * 256 + t] = g1[p * 256 + t];
            l2[p * 256 + t] = g2[p * 256 + t];
        }
    }
    float qv  = q_all[bo * 256 + t];    // prescaled by SC
    float wl  = w_logit[lane];
    float we2 = 2.0f * wl;
    float sumw = wl;
    #pragma unroll
    for (int sft = 1; sft < 64; sft <<= 1) sumw += __shfl_xor(sumw, sft);
    const float bl  = b_logit[0];
    const float lsc = LOG2E / temp[0];
    __syncthreads();

    // tanh+logit: wave w = head, lane covers m = 2*lane, 2*lane+1
    float acc0 = 0.f, acc1 = 0.f;
    const __half2* c2p = (const __half2*)s_ctx;
    #pragma unroll 8
    for (int e = 0; e < 64; ++e) {
        float2 cf = __half22float2(c2p[e * 64 + lane]);
        float qe = rl(qv, e);
        float w2 = rl(we2, e);
        float r0 = __builtin_amdgcn_rcpf(1.0f + EXP2F(cf.x + qe));
        float r1 = __builtin_amdgcn_rcpf(1.0f + EXP2F(cf.y + qe));
        acc0 = fmaf(w2, r0, acc0);   // acc = sum we*2*r ; logit = sumw - acc
        acc1 = fmaf(w2, r1, acc1);
    }
    float l0 = (sumw - acc0 + bl) * lsc;
    float l1 = (sumw - acc1 + bl) * lsc;
    float mx = fmaxf(l0, l1);
    #pragma unroll
    for (int sft = 1; sft < 64; sft <<= 1) mx = fmaxf(mx, __shfl_xor(mx, sft));
    float e0 = EXP2F(l0 - mx);
    float e1 = EXP2F(l1 - mx);
    float sum = e0 + e1;
    #pragma unroll
    for (int sft = 1; sft < 64; sft <<= 1) sum += __shfl_xor(sum, sft);
    float rs = __builtin_amdgcn_rcpf(sum);
    s_prob[(2 * lane) * H + w]     = e0 * rs;
    s_prob[(2 * lane + 1) * H + w] = e1 * rs;
    __syncthreads();

    // cooperative heads: wave w covers m in [32w,32w+32), all 4 heads; lane = e
    float h0 = 0.f, h1 = 0.f, h2 = 0.f, h3 = 0.f;
    #pragma unroll 8
    for (int i = 0; i < 32; ++i) {
        int m = 32 * w + i;
        float4 p = *(const float4*)(&s_prob[m * 4]);        // uniform b128
        float mv = __half2float(s_mem[m * 64 + lane]);
        h0 = fmaf(p.x, mv, h0);
        h1 = fmaf(p.y, mv, h1);
        h2 = fmaf(p.z, mv, h2);
        h3 = fmaf(p.w, mv, h3);
    }
    s_part[0 * 256 + w * 64 + lane] = h0;
    s_part[1 * 256 + w * 64 + lane] = h1;
    s_part[2 * 256 + w * 64 + lane] = h2;
    s_part[3 * 256 + w * 64 + lane] = h3;
    __syncthreads();
    // final: thread t -> (h = w, e = lane); leaky relu; fp16 store
    float hv = s_part[w * 256 + lane] + s_part[w * 256 + 64 + lane]
             + s_part[w * 256 + 128 + lane] + s_part[w * 256 + 192 + lane];
    hv = (hv > 0.f) ? hv : 0.01f * hv;
    heads_h[(size_t)bo * 256 + t] = __float2half_rn(hv);
}

// ============ post: out = heads @ W_rh + b_rh ; 8 rows/block, 512 threads ====
__global__ __launch_bounds__(512) void post_kernel(
    const __half* __restrict__ heads_h, const float* __restrict__ W_rh,
    const float* __restrict__ b_rh, float* __restrict__ out)
{
    __shared__ __half s_h[8 * 256];     // 4KB
    const int t = threadIdx.x, lane = t & 63, r = t >> 6;   // wave = row
    const int r0 = blockIdx.x * 8;
    ((uint2*)s_h)[t] = ((const uint2*)(heads_h + (size_t)r0 * 256))[t];
    __syncthreads();
    const __half2* hr = (const __half2*)(s_h + r * 256);
    const float* Wp = W_rh + lane;
    float acc = 0.f;
    #pragma unroll 8
    for (int jp = 0; jp < 128; ++jp) {
        float2 hh = __half22float2(hr[jp]);    // uniform per wave
        acc = fmaf(hh.x, Wp[(2 * jp) * 64], acc);
        acc = fmaf(hh.y, Wp[(2 * jp + 1) * 64], acc);
    }
    out[(size_t)(r0 + r) * 64 + lane] = acc + b_rh[lane];
}

extern "C" void kernel_launch(void* const* d_in, const int* in_sizes, int n_in,
                              void* d_out, int out_size, void* d_ws, size_t ws_size,
                              hipStream_t stream) {
    const float* query   = (const float*)d_in[0];
    const float* context = (const float*)d_in[1];
    const float* memory  = (const float*)d_in[2];
    const float* W_ch    = (const float*)d_in[3];
    const float* b_ch    = (const float*)d_in[4];
    const float* w_logit = (const float*)d_in[5];
    const float* b_logit = (const float*)d_in[6];
    const float* W_rh    = (const float*)d_in[7];
    const float* b_rh    = (const float*)d_in[8];
    const float* temp    = (const float*)d_in[9];
    float* out = (float*)d_out;

    // workspace carve: ctx_T 512K | mem_h 512K | q_all 2M | heads_h 1M  (4MB total)
    __half* ctx_T   = (__half*)d_ws;
    __half* mem_h   = ctx_T + (size_t)B * E * M;
    float*  q_all   = (float*)(mem_h + (size_t)B * M * E);
    __half* heads_h = (__half*)(q_all + (size_t)B * O * H * E);

    prep_kernel<<<544, 256, 0, stream>>>(query, context, memory, W_ch, b_ch,
                                         ctx_T, mem_h, q_all);
    attn_main<<<B * O, 256, 0, stream>>>(ctx_T, mem_h, q_all, w_logit,
                                         b_logit, temp, heads_h);
    post_kernel<<<256, 512, 0, stream>>>(heads_h, W_rh, b_rh, out);
}